// Round 1
// baseline (662.232 us; speedup 1.0000x reference)
//
#include <hip/hip_runtime.h>
#include <stdint.h>

// Problem constants
#define BATCH 32
#define SEQ   2048
#define HDIM  1024

typedef short short8 __attribute__((ext_vector_type(8)));
typedef float f32x4 __attribute__((ext_vector_type(4)));

// A-tile LDS row stride (elements): 1024 + 8 pad -> 2064B row stride.
// (2064/4)%32 = 4-bank shift per row -> 16 same-k lanes land 2-way max (free).
#define LDS_K 1032

__device__ __forceinline__ unsigned short f2b(float f) {
    unsigned u = __float_as_uint(f);
    u += 0x7FFFu + ((u >> 16) & 1u);   // round-to-nearest-even
    return (unsigned short)(u >> 16);
}

__device__ __forceinline__ float fast_tanh(float x) {
    // tanh(x) = 1 - 2/(1+e^{2x}); saturates correctly at +-inf
    float ex = __expf(2.0f * x);
    return 1.0f - 2.0f / (ex + 1.0f);
}

// ---------------------------------------------------------------------------
// Kernel 1: per k-row (grid=1024):
//   (a) convert We row k (attn_w[k][1024..2048)) to bf16 -> we_bf[k][0..1024)
//   (b) qb[b][k] = dot(hidden[b,:], attn_w[k][0..1024)) + attn_b[k]
// ---------------------------------------------------------------------------
__global__ __launch_bounds__(256) void prep_kernel(
    const float* __restrict__ hidden, const float* __restrict__ attn_w,
    const float* __restrict__ attn_b, unsigned short* __restrict__ we_bf,
    float* __restrict__ qb) {
    int k = blockIdx.x;
    int tid = threadIdx.x;

    // (a) convert We row
    {
        const float4* src = (const float4*)(attn_w + (size_t)k * 2048 + 1024);
        float4 v = src[tid];  // 256 threads * 4 floats = 1024
        ushort4 o;
        o.x = f2b(v.x); o.y = f2b(v.y); o.z = f2b(v.z); o.w = f2b(v.w);
        ((ushort4*)(we_bf + (size_t)k * HDIM))[tid] = o;
    }

    // (b) qb
    float part[BATCH];
#pragma unroll
    for (int b = 0; b < BATCH; ++b) part[b] = 0.0f;
    const float* wrow = attn_w + (size_t)k * 2048;
    for (int h = tid; h < HDIM; h += 256) {
        float w = wrow[h];
#pragma unroll
        for (int b = 0; b < BATCH; ++b) part[b] += w * hidden[b * HDIM + h];
    }
    __shared__ float red[4][BATCH];
    int lane = tid & 63, wv = tid >> 6;
#pragma unroll
    for (int b = 0; b < BATCH; ++b) {
        float v = part[b];
        v += __shfl_xor(v, 1);  v += __shfl_xor(v, 2);  v += __shfl_xor(v, 4);
        v += __shfl_xor(v, 8);  v += __shfl_xor(v, 16); v += __shfl_xor(v, 32);
        if (lane == 0) red[wv][b] = v;
    }
    __syncthreads();
    if (tid < BATCH) {
        float v = red[0][tid] + red[1][tid] + red[2][tid] + red[3][tid] + attn_b[k];
        qb[(size_t)tid * HDIM + k] = v;   // qb[b][k]
    }
}

// ---------------------------------------------------------------------------
// Kernel 2: scores[b][s] = sum_n v[n] * tanh(qb[b][n] + sum_k enc[b,s,k]*We[n,k])
// Block: 512 threads (8 waves). M-tile = 64 rows (one b, 64 s). A (enc rows,
// bf16) resident full-K in LDS; B (We bf16) streamed from global (L2-resident).
// Each wave owns 128 N-columns; 4m x 4n register blocking of 16x16x32 MFMA.
// ---------------------------------------------------------------------------
__global__ __launch_bounds__(512, 2) void score_gemm_kernel(
    const float* __restrict__ enc, const unsigned short* __restrict__ we_bf,
    const float* __restrict__ qb, const float* __restrict__ v_w,
    float* __restrict__ scores) {
    extern __shared__ char smem[];
    unsigned short* Als = (unsigned short*)smem;                 // 64 x LDS_K bf16
    float* qb_lds = (float*)(smem + 64 * LDS_K * 2);             // 1024 f32
    float* v_lds  = qb_lds + HDIM;                               // 1024 f32
    float* red    = v_lds + HDIM;                                // 8*64 f32

    int tid = threadIdx.x;
    int b   = blockIdx.x >> 5;          // 32 s-tiles per batch
    int s0  = (blockIdx.x & 31) * 64;
    const float* arow = enc + ((size_t)b * SEQ + s0) * HDIM;

    // stage qb row + v
    qb_lds[tid]        = qb[(size_t)b * HDIM + tid];
    v_lds[tid]         = v_w[tid];
    if (tid < 512) {    // always true; covers second half
        qb_lds[tid + 512] = qb[(size_t)b * HDIM + tid + 512];
        v_lds[tid + 512]  = v_w[tid + 512];
    }

    // stage A: 64 rows x 1024 fp32 -> bf16 LDS (8192 chunks of 8 floats)
#pragma unroll
    for (int it = 0; it < 16; ++it) {
        int c   = it * 512 + tid;
        int row = c >> 7;          // 128 chunks per row
        int c8  = c & 127;
        const float4* g = (const float4*)(arow + (size_t)row * HDIM + c8 * 8);
        float4 x = g[0], y = g[1];
        short8 o;
        o[0] = (short)f2b(x.x); o[1] = (short)f2b(x.y);
        o[2] = (short)f2b(x.z); o[3] = (short)f2b(x.w);
        o[4] = (short)f2b(y.x); o[5] = (short)f2b(y.y);
        o[6] = (short)f2b(y.z); o[7] = (short)f2b(y.w);
        *(short8*)(Als + row * LDS_K + c8 * 8) = o;
    }
    __syncthreads();

    int lane = tid & 63;
    int w    = tid >> 6;            // wave 0..7, owns N range [w*128, w*128+128)
    int l15  = lane & 15, q = lane >> 4;

    const unsigned short* bbase = we_bf + ((size_t)(w * 128 + l15)) * HDIM + q * 8;
    const unsigned short* albase = Als + l15 * LDS_K + q * 8;

    float sc[4][4];                 // [mt][r] partial scores for row mt*16+q*4+r
#pragma unroll
    for (int mt = 0; mt < 4; ++mt)
#pragma unroll
        for (int r = 0; r < 4; ++r) sc[mt][r] = 0.0f;

    for (int g = 0; g < 2; ++g) {   // two n-groups of 64 columns
        f32x4 acc[4][4];
#pragma unroll
        for (int mt = 0; mt < 4; ++mt)
#pragma unroll
            for (int nt = 0; nt < 4; ++nt) acc[mt][nt] = (f32x4)0.0f;

        const unsigned short* bg = bbase + (size_t)g * 64 * HDIM;
        for (int ks = 0; ks < 32; ++ks) {
            int ko = ks * 32;
            short8 af[4], bf[4];
#pragma unroll
            for (int mt = 0; mt < 4; ++mt)
                af[mt] = *(const short8*)(albase + mt * 16 * LDS_K + ko);
#pragma unroll
            for (int nt = 0; nt < 4; ++nt)
                bf[nt] = *(const short8*)(bg + (size_t)nt * 16 * HDIM + ko);
#pragma unroll
            for (int mt = 0; mt < 4; ++mt)
#pragma unroll
                for (int nt = 0; nt < 4; ++nt)
                    acc[mt][nt] = __builtin_amdgcn_mfma_f32_16x16x32_bf16(
                        af[mt], bf[nt], acc[mt][nt], 0, 0, 0);
        }

        // epilogue: sc[m] += v[n] * tanh(qb[n] + C[m][n])
#pragma unroll
        for (int nt = 0; nt < 4; ++nt) {
            int n = w * 128 + g * 64 + nt * 16 + l15;
            float qv = qb_lds[n], vv = v_lds[n];
#pragma unroll
            for (int mt = 0; mt < 4; ++mt)
#pragma unroll
                for (int r = 0; r < 4; ++r)
                    sc[mt][r] += vv * fast_tanh(acc[mt][nt][r] + qv);
        }
    }

    // reduce across the 16 n-lanes (same q)
#pragma unroll
    for (int mt = 0; mt < 4; ++mt)
#pragma unroll
        for (int r = 0; r < 4; ++r) {
            float v = sc[mt][r];
            v += __shfl_xor(v, 1); v += __shfl_xor(v, 2);
            v += __shfl_xor(v, 4); v += __shfl_xor(v, 8);
            sc[mt][r] = v;
        }
    if (l15 == 0) {
#pragma unroll
        for (int mt = 0; mt < 4; ++mt)
#pragma unroll
            for (int r = 0; r < 4; ++r)
                red[w * 64 + mt * 16 + q * 4 + r] = sc[mt][r];
    }
    __syncthreads();
    if (tid < 64) {
        float t = 0.0f;
#pragma unroll
        for (int w2 = 0; w2 < 8; ++w2) t += red[w2 * 64 + tid];
        scores[(size_t)b * SEQ + s0 + tid] = t;
    }
}

// ---------------------------------------------------------------------------
// Kernel 3: softmax over S per batch; writes attn_weights to d_out[65536..),
// zeroes context slots, copies hidden into output rows.
// ---------------------------------------------------------------------------
__global__ __launch_bounds__(256) void softmax_kernel(
    const float* __restrict__ scores, const float* __restrict__ hidden,
    float* out) {
    int b = blockIdx.x, tid = threadIdx.x;
    const float* srow = scores + (size_t)b * SEQ;
    __shared__ float redm[4];
    __shared__ float reds[4];
    int lane = tid & 63, wv = tid >> 6;

    float loc[8];
    float m = -1e30f;
#pragma unroll
    for (int i = 0; i < 8; ++i) {
        loc[i] = srow[tid + i * 256];
        m = fmaxf(m, loc[i]);
    }
#pragma unroll
    for (int d = 1; d < 64; d <<= 1) m = fmaxf(m, __shfl_xor(m, d));
    if (lane == 0) redm[wv] = m;
    __syncthreads();
    m = fmaxf(fmaxf(redm[0], redm[1]), fmaxf(redm[2], redm[3]));

    float sum = 0.0f;
#pragma unroll
    for (int i = 0; i < 8; ++i) {
        float e = __expf(loc[i] - m);
        loc[i] = e;
        sum += e;
    }
#pragma unroll
    for (int d = 1; d < 64; d <<= 1) sum += __shfl_xor(sum, d);
    if (lane == 0) reds[wv] = sum;
    __syncthreads();
    sum = reds[0] + reds[1] + reds[2] + reds[3];
    float inv = 1.0f / sum;

#pragma unroll
    for (int i = 0; i < 8; ++i)
        out[BATCH * SEQ + (size_t)b * SEQ + tid + i * 256] = loc[i] * inv;

    // zero context region + copy hidden (output row layout: [context | hidden])
    for (int i = tid; i < HDIM; i += 256) {
        out[(size_t)b * 2048 + i] = 0.0f;
        out[(size_t)b * 2048 + 1024 + i] = hidden[(size_t)b * HDIM + i];
    }
}

// ---------------------------------------------------------------------------
// Kernel 4: context[b][h] += sum_s w[b][s] * enc[b][s][h]
// grid = 32 b x 4 h-chunks x 8 s-chunks, atomicAdd partial sums.
// ---------------------------------------------------------------------------
__global__ __launch_bounds__(256) void context_kernel(
    const float* __restrict__ enc, const float* weights_src, float* out) {
    int id = blockIdx.x;
    int sc = id & 7, hc = (id >> 3) & 3, b = id >> 5;
    int tid = threadIdx.x;
    __shared__ float wl[256];
    wl[tid] = weights_src[BATCH * SEQ + (size_t)b * SEQ + sc * 256 + tid];
    __syncthreads();
    const float* ebase = enc + ((size_t)b * SEQ + sc * 256) * HDIM + hc * 256 + tid;
    float acc = 0.0f;
#pragma unroll 4
    for (int s = 0; s < 256; ++s) acc += wl[s] * ebase[(size_t)s * HDIM];
    atomicAdd(&out[(size_t)b * 2048 + hc * 256 + tid], acc);
}

// ---------------------------------------------------------------------------
extern "C" void kernel_launch(void* const* d_in, const int* in_sizes, int n_in,
                              void* d_out, int out_size, void* d_ws, size_t ws_size,
                              hipStream_t stream) {
    const float* hidden = (const float*)d_in[0];
    const float* enc    = (const float*)d_in[1];
    const float* attn_w = (const float*)d_in[2];
    const float* attn_b = (const float*)d_in[3];
    const float* v_w    = (const float*)d_in[4];
    float* out = (float*)d_out;

    char* ws = (char*)d_ws;
    unsigned short* we_bf = (unsigned short*)ws;                        // 2 MB
    float* qb     = (float*)(ws + (size_t)2097152);                     // 128 KB
    float* scores = (float*)(ws + (size_t)2097152 + 131072);            // 256 KB

    prep_kernel<<<1024, 256, 0, stream>>>(hidden, attn_w, attn_b, we_bf, qb);

    size_t smem = (size_t)64 * LDS_K * 2 + HDIM * 4 * 2 + 8 * 64 * 4;   // 142336 B
    score_gemm_kernel<<<1024, 512, smem, stream>>>(enc, we_bf, qb, v_w, scores);

    softmax_kernel<<<32, 256, 0, stream>>>(scores, hidden, out);

    context_kernel<<<1024, 256, 0, stream>>>(enc, out, out);
}

// Round 2
// 602.992 us; speedup vs baseline: 1.0982x; 1.0982x over previous
//
#include <hip/hip_runtime.h>
#include <stdint.h>

#define BATCH 32
#define SEQ   2048
#define HDIM  1024

typedef short short8 __attribute__((ext_vector_type(8)));
typedef float f32x4 __attribute__((ext_vector_type(4)));

__device__ __forceinline__ unsigned short f2b(float f) {
    unsigned u = __float_as_uint(f);
    u += 0x7FFFu + ((u >> 16) & 1u);   // round-to-nearest-even
    return (unsigned short)(u >> 16);
}
__device__ __forceinline__ float b2f(unsigned short u) {
    return __uint_as_float(((unsigned)u) << 16);
}
__device__ __forceinline__ float fast_tanh(float x) {
    float ex = __expf(2.0f * x);
    return 1.0f - 2.0f / (ex + 1.0f);
}

// async global->LDS, 16B per lane. LDS dest must be wave-uniform base;
// HW adds lane*16.
__device__ __forceinline__ void gl2lds16(const unsigned short* g, unsigned short* l) {
    __builtin_amdgcn_global_load_lds(
        (const __attribute__((address_space(1))) unsigned int*)g,
        (__attribute__((address_space(3))) unsigned int*)l, 16, 0, 0);
}

// ---------------------------------------------------------------------------
// Kernel 0: enc fp32 -> bf16 (32M elements). 32768 blocks x 256 thr x 8 elem.
// ---------------------------------------------------------------------------
__global__ __launch_bounds__(256) void enc_convert(
    const float* __restrict__ enc, unsigned short* __restrict__ enc_bf) {
    size_t i = ((size_t)blockIdx.x * 256 + threadIdx.x) * 8;
    const float4* s = (const float4*)(enc + i);
    float4 a = s[0], b = s[1];
    short8 o;
    o[0] = (short)f2b(a.x); o[1] = (short)f2b(a.y);
    o[2] = (short)f2b(a.z); o[3] = (short)f2b(a.w);
    o[4] = (short)f2b(b.x); o[5] = (short)f2b(b.y);
    o[6] = (short)f2b(b.z); o[7] = (short)f2b(b.w);
    *(short8*)(enc_bf + i) = o;
}

// ---------------------------------------------------------------------------
// Kernel 1: per k-row (grid=1024): We row -> bf16; qb[b][k] = hidden.Wh^T + b
// Also zeroes scores (64 elems per block).
// ---------------------------------------------------------------------------
__global__ __launch_bounds__(256) void prep_kernel(
    const float* __restrict__ hidden, const float* __restrict__ attn_w,
    const float* __restrict__ attn_b, unsigned short* __restrict__ we_bf,
    float* __restrict__ qb, float* __restrict__ scores) {
    int k = blockIdx.x;
    int tid = threadIdx.x;

    if (tid < 64) scores[(size_t)k * 64 + tid] = 0.0f;

    {
        const float4* src = (const float4*)(attn_w + (size_t)k * 2048 + 1024);
        float4 v = src[tid];
        ushort4 o;
        o.x = f2b(v.x); o.y = f2b(v.y); o.z = f2b(v.z); o.w = f2b(v.w);
        ((ushort4*)(we_bf + (size_t)k * HDIM))[tid] = o;
    }

    float part[BATCH];
#pragma unroll
    for (int b = 0; b < BATCH; ++b) part[b] = 0.0f;
    const float* wrow = attn_w + (size_t)k * 2048;
    for (int h = tid; h < HDIM; h += 256) {
        float w = wrow[h];
#pragma unroll
        for (int b = 0; b < BATCH; ++b) part[b] += w * hidden[b * HDIM + h];
    }
    __shared__ float red[4][BATCH];
    int lane = tid & 63, wv = tid >> 6;
#pragma unroll
    for (int b = 0; b < BATCH; ++b) {
        float v = part[b];
        v += __shfl_xor(v, 1);  v += __shfl_xor(v, 2);  v += __shfl_xor(v, 4);
        v += __shfl_xor(v, 8);  v += __shfl_xor(v, 16); v += __shfl_xor(v, 32);
        if (lane == 0) red[wv][b] = v;
    }
    __syncthreads();
    if (tid < BATCH) {
        float v = red[0][tid] + red[1][tid] + red[2][tid] + red[3][tid] + attn_b[k];
        qb[(size_t)tid * HDIM + k] = v;
    }
}

// ---------------------------------------------------------------------------
// Kernel 2: score GEMM. m97-style 128x128 tile, BK=64, 256 thr = 4 waves 2x2.
// A = enc_bf (M=65536), B = we_bf (N=1024, 8 n-tiles). global_load_lds 16B
// staging with XOR chunk swizzle (read side perfectly bank-balanced).
// Epilogue: scores[b][s] += sum_n v[n]*tanh(qb[b][n] + C[s][n]) via atomicAdd.
// ---------------------------------------------------------------------------
__global__ __launch_bounds__(256) void score_gemm_kernel(
    const unsigned short* __restrict__ enc_bf, const unsigned short* __restrict__ we_bf,
    const float* __restrict__ qb, const float* __restrict__ v_w,
    float* __restrict__ scores) {
    __shared__ unsigned short Als[128 * 64];   // 16 KB, row-major, 64-short rows
    __shared__ unsigned short Bls[128 * 64];   // 16 KB

    int tid  = threadIdx.x;
    int lane = tid & 63, w = tid >> 6;
    int wm = w & 1, wn = w >> 1;
    int i15 = lane & 15, q = lane >> 4;

    int ntile = blockIdx.x & 7;
    int mtile = blockIdx.x >> 3;
    int b  = mtile >> 4;
    int s0 = (mtile & 15) * 128;

    const unsigned short* Ag = enc_bf + ((size_t)(b * SEQ + s0)) * HDIM;
    const unsigned short* Bg = we_bf + (size_t)ntile * 128 * HDIM;

    // staging: instruction (w,j) covers rows r0=(w*4+j)*8 .. +8, 1 KB LDS.
    // lane i -> row r0+(i>>3), LDS chunk pos i&7; content chunk = pos^(row&7).
    int srow   = lane >> 3;
    int schunk = (lane & 7) ^ srow;
    const unsigned short* Ag_l = Ag + (size_t)srow * HDIM + schunk * 8;
    const unsigned short* Bg_l = Bg + (size_t)srow * HDIM + schunk * 8;
    unsigned short* Al_w = Als + (w * 4) * 512;
    unsigned short* Bl_w = Bls + (w * 4) * 512;

    f32x4 acc[4][4];
#pragma unroll
    for (int mt = 0; mt < 4; ++mt)
#pragma unroll
        for (int nt = 0; nt < 4; ++nt) acc[mt][nt] = (f32x4)0.0f;

    const unsigned short* Abase = Als + (wm * 64 + i15) * 64;
    const unsigned short* Bbase = Bls + (wn * 64 + i15) * 64;

    for (int ks = 0; ks < 16; ++ks) {
        if (ks) __syncthreads();
        int k0 = ks * 64;
#pragma unroll
        for (int j = 0; j < 4; ++j) {
            size_t roff = (size_t)((w * 4 + j) * 8) * HDIM + k0;
            gl2lds16(Ag_l + roff, Al_w + j * 512);
            gl2lds16(Bg_l + roff, Bl_w + j * 512);
        }
        __syncthreads();
#pragma unroll
        for (int k2 = 0; k2 < 2; ++k2) {
            int xr = ((k2 * 4 + q) ^ (i15 & 7)) * 8;
            short8 af[4], bf[4];
#pragma unroll
            for (int mt = 0; mt < 4; ++mt)
                af[mt] = *(const short8*)(Abase + mt * 16 * 64 + xr);
#pragma unroll
            for (int nt = 0; nt < 4; ++nt)
                bf[nt] = *(const short8*)(Bbase + nt * 16 * 64 + xr);
#pragma unroll
            for (int mt = 0; mt < 4; ++mt)
#pragma unroll
                for (int nt = 0; nt < 4; ++nt)
                    acc[mt][nt] = __builtin_amdgcn_mfma_f32_16x16x32_bf16(
                        af[mt], bf[nt], acc[mt][nt], 0, 0, 0);
        }
    }

    // epilogue: C layout col=lane&15 (n), row=q*4+reg (m)
    float sc[4][4];
#pragma unroll
    for (int mt = 0; mt < 4; ++mt)
#pragma unroll
        for (int r = 0; r < 4; ++r) sc[mt][r] = 0.0f;

#pragma unroll
    for (int nt = 0; nt < 4; ++nt) {
        int n = ntile * 128 + wn * 64 + nt * 16 + i15;
        float qv = qb[(size_t)b * HDIM + n];
        float vv = v_w[n];
#pragma unroll
        for (int mt = 0; mt < 4; ++mt)
#pragma unroll
            for (int r = 0; r < 4; ++r)
                sc[mt][r] += vv * fast_tanh(acc[mt][nt][r] + qv);
    }
#pragma unroll
    for (int mt = 0; mt < 4; ++mt)
#pragma unroll
        for (int r = 0; r < 4; ++r) {
            float v = sc[mt][r];
            v += __shfl_xor(v, 1); v += __shfl_xor(v, 2);
            v += __shfl_xor(v, 4); v += __shfl_xor(v, 8);
            if (i15 == 0)
                atomicAdd(&scores[(size_t)b * SEQ + s0 + wm * 64 + mt * 16 + q * 4 + r], v);
        }
}

// ---------------------------------------------------------------------------
// Kernel 3: softmax over S per batch; writes attn_weights, zeroes context
// slots, copies hidden.
// ---------------------------------------------------------------------------
__global__ __launch_bounds__(256) void softmax_kernel(
    const float* __restrict__ scores, const float* __restrict__ hidden,
    float* out) {
    int b = blockIdx.x, tid = threadIdx.x;
    const float* srow = scores + (size_t)b * SEQ;
    __shared__ float redm[4];
    __shared__ float reds[4];
    int lane = tid & 63, wv = tid >> 6;

    float loc[8];
    float m = -1e30f;
#pragma unroll
    for (int i = 0; i < 8; ++i) {
        loc[i] = srow[tid + i * 256];
        m = fmaxf(m, loc[i]);
    }
#pragma unroll
    for (int d = 1; d < 64; d <<= 1) m = fmaxf(m, __shfl_xor(m, d));
    if (lane == 0) redm[wv] = m;
    __syncthreads();
    m = fmaxf(fmaxf(redm[0], redm[1]), fmaxf(redm[2], redm[3]));

    float sum = 0.0f;
#pragma unroll
    for (int i = 0; i < 8; ++i) {
        float e = __expf(loc[i] - m);
        loc[i] = e;
        sum += e;
    }
#pragma unroll
    for (int d = 1; d < 64; d <<= 1) sum += __shfl_xor(sum, d);
    if (lane == 0) reds[wv] = sum;
    __syncthreads();
    sum = reds[0] + reds[1] + reds[2] + reds[3];
    float inv = 1.0f / sum;

#pragma unroll
    for (int i = 0; i < 8; ++i)
        out[BATCH * SEQ + (size_t)b * SEQ + tid + i * 256] = loc[i] * inv;

    for (int i = tid; i < HDIM; i += 256) {
        out[(size_t)b * 2048 + i] = 0.0f;
        out[(size_t)b * 2048 + 1024 + i] = hidden[(size_t)b * HDIM + i];
    }
}

// ---------------------------------------------------------------------------
// Kernel 4: context from bf16 enc. grid = 32 b x 16 s-chunks (128 rows).
// Each thread: 4 h via ushort4; atomicAdd partials.
// ---------------------------------------------------------------------------
__global__ __launch_bounds__(256) void context_kernel(
    const unsigned short* __restrict__ enc_bf, const float* weights_src,
    float* out) {
    int id = blockIdx.x;
    int scid = id & 15, b = id >> 4;
    int tid = threadIdx.x;
    __shared__ float wl[128];
    if (tid < 128)
        wl[tid] = weights_src[BATCH * SEQ + (size_t)b * SEQ + scid * 128 + tid];
    __syncthreads();
    const unsigned short* ebase =
        enc_bf + ((size_t)(b * SEQ + scid * 128)) * HDIM + tid * 4;
    float a0 = 0.f, a1 = 0.f, a2 = 0.f, a3 = 0.f;
#pragma unroll 4
    for (int s = 0; s < 128; ++s) {
        ushort4 u = *(const ushort4*)(ebase + (size_t)s * HDIM);
        float w = wl[s];
        a0 += w * b2f(u.x); a1 += w * b2f(u.y);
        a2 += w * b2f(u.z); a3 += w * b2f(u.w);
    }
    float* o = out + (size_t)b * 2048 + tid * 4;
    atomicAdd(o + 0, a0); atomicAdd(o + 1, a1);
    atomicAdd(o + 2, a2); atomicAdd(o + 3, a3);
}

// ---------------------------------------------------------------------------
extern "C" void kernel_launch(void* const* d_in, const int* in_sizes, int n_in,
                              void* d_out, int out_size, void* d_ws, size_t ws_size,
                              hipStream_t stream) {
    const float* hidden = (const float*)d_in[0];
    const float* enc    = (const float*)d_in[1];
    const float* attn_w = (const float*)d_in[2];
    const float* attn_b = (const float*)d_in[3];
    const float* v_w    = (const float*)d_in[4];
    float* out = (float*)d_out;

    char* ws = (char*)d_ws;
    unsigned short* we_bf = (unsigned short*)ws;                              // 2 MB
    float* qb     = (float*)(ws + (size_t)2097152);                           // 128 KB
    float* scores = (float*)(ws + (size_t)2097152 + 131072);                  // 256 KB
    unsigned short* enc_bf = (unsigned short*)(ws + (size_t)2097152 + 131072 + 262144); // 128 MB

    enc_convert<<<32768, 256, 0, stream>>>(enc, enc_bf);
    prep_kernel<<<1024, 256, 0, stream>>>(hidden, attn_w, attn_b, we_bf, qb, scores);
    score_gemm_kernel<<<4096, 256, 0, stream>>>(enc_bf, we_bf, qb, v_w, scores);
    softmax_kernel<<<32, 256, 0, stream>>>(scores, hidden, out);
    context_kernel<<<512, 256, 0, stream>>>(enc_bf, out, out);
}

// Round 3
// 548.208 us; speedup vs baseline: 1.2080x; 1.0999x over previous
//
#include <hip/hip_runtime.h>
#include <stdint.h>

#define BATCH 32
#define SEQ   2048
#define HDIM  1024

typedef short short8 __attribute__((ext_vector_type(8)));
typedef float f32x4 __attribute__((ext_vector_type(4)));

__device__ __forceinline__ unsigned short f2b(float f) {
    unsigned u = __float_as_uint(f);
    u += 0x7FFFu + ((u >> 16) & 1u);   // round-to-nearest-even
    return (unsigned short)(u >> 16);
}
// pack hi16(a) | hi16(b)<<16 in one v_perm_b32 (bf16 truncation)
__device__ __forceinline__ unsigned pk_bf16(float a, float b) {
    return __builtin_amdgcn_perm(__float_as_uint(b), __float_as_uint(a), 0x07060302u);
}
__device__ __forceinline__ float fast_tanh(float x) {
    float ex = __expf(2.0f * x);
    return 1.0f - 2.0f / (ex + 1.0f);
}
__device__ __forceinline__ void gl2lds16(const unsigned short* g, unsigned short* l) {
    __builtin_amdgcn_global_load_lds(
        (const __attribute__((address_space(1))) unsigned int*)g,
        (__attribute__((address_space(3))) unsigned int*)l, 16, 0, 0);
}

// ---------------------------------------------------------------------------
// Kernel 1: per k-row (grid=1024): We row -> bf16 (RNE); qb = hidden.Wh^T + b;
// zero scores.
// ---------------------------------------------------------------------------
__global__ __launch_bounds__(256) void prep_kernel(
    const float* __restrict__ hidden, const float* __restrict__ attn_w,
    const float* __restrict__ attn_b, unsigned short* __restrict__ we_bf,
    float* __restrict__ qb, float* __restrict__ scores) {
    int k = blockIdx.x;
    int tid = threadIdx.x;

    if (tid < 64) scores[(size_t)k * 64 + tid] = 0.0f;

    {
        const float4* src = (const float4*)(attn_w + (size_t)k * 2048 + 1024);
        float4 v = src[tid];
        ushort4 o;
        o.x = f2b(v.x); o.y = f2b(v.y); o.z = f2b(v.z); o.w = f2b(v.w);
        ((ushort4*)(we_bf + (size_t)k * HDIM))[tid] = o;
    }

    float part[BATCH];
#pragma unroll
    for (int b = 0; b < BATCH; ++b) part[b] = 0.0f;
    const float* wrow = attn_w + (size_t)k * 2048;
    for (int h = tid; h < HDIM; h += 256) {
        float w = wrow[h];
#pragma unroll
        for (int b = 0; b < BATCH; ++b) part[b] += w * hidden[b * HDIM + h];
    }
    __shared__ float red[4][BATCH];
    int lane = tid & 63, wv = tid >> 6;
#pragma unroll
    for (int b = 0; b < BATCH; ++b) {
        float v = part[b];
        v += __shfl_xor(v, 1);  v += __shfl_xor(v, 2);  v += __shfl_xor(v, 4);
        v += __shfl_xor(v, 8);  v += __shfl_xor(v, 16); v += __shfl_xor(v, 32);
        if (lane == 0) red[wv][b] = v;
    }
    __syncthreads();
    if (tid < BATCH) {
        float v = red[0][tid] + red[1][tid] + red[2][tid] + red[3][tid] + attn_b[k];
        qb[(size_t)tid * HDIM + k] = v;
    }
}

// ---------------------------------------------------------------------------
// Kernel 2: score GEMM, 128x128 tile, BK=64. A = enc fp32 read directly
// (register prefetch overlapped with MFMA, v_perm bf16 truncation,
// ds_write_b128 into XOR-swizzled LDS). B = we_bf via global_load_lds.
// XCD swizzle: the 8 ntile-blocks of an mtile share blockIdx%8 -> same XCD,
// adjacent in per-XCD dispatch order -> A fetched from HBM ~once.
// ---------------------------------------------------------------------------
__global__ __launch_bounds__(256, 3) void score_gemm_kernel(
    const float* __restrict__ enc, const unsigned short* __restrict__ we_bf,
    const float* __restrict__ qb, const float* __restrict__ v_w,
    float* __restrict__ scores) {
    __shared__ __align__(16) unsigned short Als[128 * 64];   // 16 KB
    __shared__ __align__(16) unsigned short Bls[128 * 64];   // 16 KB

    int tid  = threadIdx.x;
    int lane = tid & 63, w = tid >> 6;
    int wm = w & 1, wn = w >> 1;
    int i15 = lane & 15, q = lane >> 4;

    // XCD-aware decode: mtile%8 == blockIdx%8; ntile-major within XCD slot
    int raw   = blockIdx.x;
    int ntile = (raw >> 3) & 7;
    int mtile = (raw & 7) + 8 * (raw >> 6);
    int b  = mtile >> 4;
    int s0 = (mtile & 15) * 128;

    const float* Ag = enc + ((size_t)(b * SEQ + s0)) * HDIM;
    const unsigned short* Bg = we_bf + (size_t)ntile * 128 * HDIM;

    // B staging (global_load_lds): instr (w,j) -> rows (w*4+j)*8..+8
    int srow   = lane >> 3;
    int schunk = (lane & 7) ^ srow;
    const unsigned short* Bg_l = Bg + (size_t)srow * HDIM + schunk * 8;
    unsigned short* Bl_w = Bls + (w * 4) * 512;

    // A staging: j in 0..3, row = j*32 + (tid>>3), content chunk c = tid&7
    int arow = tid >> 3;
    int ac   = tid & 7;
    const float* Ag_l = Ag + (size_t)arow * HDIM + ac * 8;

    f32x4 acc[4][4];
#pragma unroll
    for (int mt = 0; mt < 4; ++mt)
#pragma unroll
        for (int nt = 0; nt < 4; ++nt) acc[mt][nt] = (f32x4)0.0f;

    const unsigned short* Abase = Als + (wm * 64 + i15) * 64;
    const unsigned short* Bbase = Bls + (wn * 64 + i15) * 64;

    // prologue: prefetch A chunk for ks=0
    float4 pre[8];
#pragma unroll
    for (int j = 0; j < 4; ++j) {
        const float4* g = (const float4*)(Ag_l + (size_t)(j * 32) * HDIM);
        pre[2 * j]     = g[0];
        pre[2 * j + 1] = g[1];
    }

    for (int ks = 0; ks < 16; ++ks) {
        __syncthreads();
        // write A (bf16 truncate) into swizzled LDS
#pragma unroll
        for (int j = 0; j < 4; ++j) {
            int r = j * 32 + arow;
            int p = ac ^ (r & 7);
            float4 x = pre[2 * j], y = pre[2 * j + 1];
            uint4 o;
            o.x = pk_bf16(x.x, x.y); o.y = pk_bf16(x.z, x.w);
            o.z = pk_bf16(y.x, y.y); o.w = pk_bf16(y.z, y.w);
            *(uint4*)(Als + r * 64 + p * 8) = o;
        }
        // stage B tile for this k-step
        int k0 = ks * 64;
#pragma unroll
        for (int j = 0; j < 4; ++j) {
            size_t roff = (size_t)((w * 4 + j) * 8) * HDIM + k0;
            gl2lds16(Bg_l + roff, Bl_w + j * 512);
        }
        __syncthreads();

        // prefetch A for next k-step (overlaps MFMA below)
        int kn = ((ks + 1) & 15) * 64;
#pragma unroll
        for (int j = 0; j < 4; ++j) {
            const float4* g = (const float4*)(Ag_l + (size_t)(j * 32) * HDIM + kn);
            pre[2 * j]     = g[0];
            pre[2 * j + 1] = g[1];
        }

#pragma unroll
        for (int k2 = 0; k2 < 2; ++k2) {
            int xr = ((k2 * 4 + q) ^ (i15 & 7)) * 8;
            short8 af[4], bf[4];
#pragma unroll
            for (int mt = 0; mt < 4; ++mt)
                af[mt] = *(const short8*)(Abase + mt * 16 * 64 + xr);
#pragma unroll
            for (int nt = 0; nt < 4; ++nt)
                bf[nt] = *(const short8*)(Bbase + nt * 16 * 64 + xr);
#pragma unroll
            for (int mt = 0; mt < 4; ++mt)
#pragma unroll
                for (int nt = 0; nt < 4; ++nt)
                    acc[mt][nt] = __builtin_amdgcn_mfma_f32_16x16x32_bf16(
                        af[mt], bf[nt], acc[mt][nt], 0, 0, 0);
        }
    }

    // epilogue: C layout col=lane&15 (n), row=q*4+reg (m)
    float sc[4][4];
#pragma unroll
    for (int mt = 0; mt < 4; ++mt)
#pragma unroll
        for (int r = 0; r < 4; ++r) sc[mt][r] = 0.0f;

#pragma unroll
    for (int nt = 0; nt < 4; ++nt) {
        int n = ntile * 128 + wn * 64 + nt * 16 + i15;
        float qv = qb[(size_t)b * HDIM + n];
        float vv = v_w[n];
#pragma unroll
        for (int mt = 0; mt < 4; ++mt)
#pragma unroll
            for (int r = 0; r < 4; ++r)
                sc[mt][r] += vv * fast_tanh(acc[mt][nt][r] + qv);
    }
#pragma unroll
    for (int mt = 0; mt < 4; ++mt)
#pragma unroll
        for (int r = 0; r < 4; ++r) {
            float v = sc[mt][r];
            v += __shfl_xor(v, 1); v += __shfl_xor(v, 2);
            v += __shfl_xor(v, 4); v += __shfl_xor(v, 8);
            if (i15 == 0)
                atomicAdd(&scores[(size_t)b * SEQ + s0 + wm * 64 + mt * 16 + q * 4 + r], v);
        }
}

// ---------------------------------------------------------------------------
// Kernel 3: softmax over S per batch; writes attn_weights, zeroes context
// slots, copies hidden.
// ---------------------------------------------------------------------------
__global__ __launch_bounds__(256) void softmax_kernel(
    const float* __restrict__ scores, const float* __restrict__ hidden,
    float* out) {
    int b = blockIdx.x, tid = threadIdx.x;
    const float* srow = scores + (size_t)b * SEQ;
    __shared__ float redm[4];
    __shared__ float reds[4];
    int lane = tid & 63, wv = tid >> 6;

    float loc[8];
    float m = -1e30f;
#pragma unroll
    for (int i = 0; i < 8; ++i) {
        loc[i] = srow[tid + i * 256];
        m = fmaxf(m, loc[i]);
    }
#pragma unroll
    for (int d = 1; d < 64; d <<= 1) m = fmaxf(m, __shfl_xor(m, d));
    if (lane == 0) redm[wv] = m;
    __syncthreads();
    m = fmaxf(fmaxf(redm[0], redm[1]), fmaxf(redm[2], redm[3]));

    float sum = 0.0f;
#pragma unroll
    for (int i = 0; i < 8; ++i) {
        float e = __expf(loc[i] - m);
        loc[i] = e;
        sum += e;
    }
#pragma unroll
    for (int d = 1; d < 64; d <<= 1) sum += __shfl_xor(sum, d);
    if (lane == 0) reds[wv] = sum;
    __syncthreads();
    sum = reds[0] + reds[1] + reds[2] + reds[3];
    float inv = 1.0f / sum;

#pragma unroll
    for (int i = 0; i < 8; ++i)
        out[BATCH * SEQ + (size_t)b * SEQ + tid + i * 256] = loc[i] * inv;

    for (int i = tid; i < HDIM; i += 256) {
        out[(size_t)b * 2048 + i] = 0.0f;
        out[(size_t)b * 2048 + 1024 + i] = hidden[(size_t)b * HDIM + i];
    }
}

// ---------------------------------------------------------------------------
// Kernel 4: context from fp32 enc. grid = 32 b x 16 s-chunks (128 rows).
// Thread handles 4 h via float4; atomicAdd partials.
// ---------------------------------------------------------------------------
__global__ __launch_bounds__(256) void context_kernel(
    const float* __restrict__ enc, const float* weights_src, float* out) {
    int id = blockIdx.x;
    int scid = id & 15, b = id >> 4;
    int tid = threadIdx.x;
    __shared__ float wl[128];
    if (tid < 128)
        wl[tid] = weights_src[BATCH * SEQ + (size_t)b * SEQ + scid * 128 + tid];
    __syncthreads();
    const float* ebase = enc + ((size_t)(b * SEQ + scid * 128)) * HDIM + tid * 4;
    float a0 = 0.f, a1 = 0.f, a2 = 0.f, a3 = 0.f;
#pragma unroll 8
    for (int s = 0; s < 128; ++s) {
        float4 e = *(const float4*)(ebase + (size_t)s * HDIM);
        float w = wl[s];
        a0 += w * e.x; a1 += w * e.y; a2 += w * e.z; a3 += w * e.w;
    }
    float* o = out + (size_t)b * 2048 + tid * 4;
    atomicAdd(o + 0, a0); atomicAdd(o + 1, a1);
    atomicAdd(o + 2, a2); atomicAdd(o + 3, a3);
}

// ---------------------------------------------------------------------------
extern "C" void kernel_launch(void* const* d_in, const int* in_sizes, int n_in,
                              void* d_out, int out_size, void* d_ws, size_t ws_size,
                              hipStream_t stream) {
    const float* hidden = (const float*)d_in[0];
    const float* enc    = (const float*)d_in[1];
    const float* attn_w = (const float*)d_in[2];
    const float* attn_b = (const float*)d_in[3];
    const float* v_w    = (const float*)d_in[4];
    float* out = (float*)d_out;

    char* ws = (char*)d_ws;
    unsigned short* we_bf = (unsigned short*)ws;                     // 2 MB
    float* qb     = (float*)(ws + (size_t)2097152);                  // 128 KB
    float* scores = (float*)(ws + (size_t)2097152 + 131072);         // 256 KB

    prep_kernel<<<1024, 256, 0, stream>>>(hidden, attn_w, attn_b, we_bf, qb, scores);
    score_gemm_kernel<<<4096, 256, 0, stream>>>(enc, we_bf, qb, v_w, scores);
    softmax_kernel<<<32, 256, 0, stream>>>(scores, hidden, out);
    context_kernel<<<512, 256, 0, stream>>>(enc, out, out);
}